// Round 3
// baseline (254.984 us; speedup 1.0000x reference)
//
#include <hip/hip_runtime.h>
#include <stdint.h>

#define NROWS 100000
#define SDIM 150
#define HDIM 150
#define KSEG 160      // per-segment K, padded 150->160
#define NKB 20        // K-steps of 32 (total K = 640)
#define NCOL 640      // 4 gates * 160 padded cols
#define BM 96
#define NTHREADS 768
#define BSLICE 40960               // B bytes per K-step slice (640 cols * 32 k * 2B)
#define ASLICE 6144                // A f16 bytes per K-step (96 rows * 64B)
#define BUFBYTES (BSLICE + ASLICE) // 47104
#define EPI_STRIDE 648             // f16 elems per epilogue row

using half8  = __attribute__((ext_vector_type(8))) _Float16;
using half2v = __attribute__((ext_vector_type(2))) _Float16;
using floatx4 = __attribute__((ext_vector_type(4))) float;

__device__ __forceinline__ float fsig(float x) {
  return __builtin_amdgcn_rcpf(1.0f + __expf(-x));
}
__device__ __forceinline__ float ftanh(float x) {
  return 2.0f * __builtin_amdgcn_rcpf(1.0f + __expf(-2.0f * x)) - 1.0f;
}

__device__ __forceinline__ void gload_lds16(const void* g, void* l) {
  __builtin_amdgcn_global_load_lds(
      (const __attribute__((address_space(1))) void*)g,
      (__attribute__((address_space(3))) void*)l, 16, 0, 0);
}

// Barrier with counted vmcnt: drains everything issued in PREVIOUS iters
// (<= VM outstanding afterward = this iter's staging), never a full drain
// in steady state. asm memory clobbers fence compiler motion around it.
#define KBAR(VM)                                              \
  do {                                                        \
    asm volatile("s_waitcnt vmcnt(" #VM ")" ::: "memory");    \
    asm volatile("s_waitcnt lgkmcnt(0)" ::: "memory");        \
    __builtin_amdgcn_s_barrier();                             \
    asm volatile("" ::: "memory");                            \
  } while (0)

// Pack W = [w_in; w_out; u_in; u_out] (600x600 fp32) into f16, K-blocked,
// XOR-swizzled layout: element (col,k) at byte
//   kb*BSLICE + col*64 + slot*16 + (k&7)*2,  kb=k>>5, slot=((k>>3)&3)^((col>>1)&3)
__global__ void pack_w_kernel(const float* __restrict__ w_in,
                              const float* __restrict__ w_out,
                              const float* __restrict__ u_in,
                              const float* __restrict__ u_out,
                              _Float16* __restrict__ wblk) {
  int idx = blockIdx.x * 256 + threadIdx.x;
  if (idx >= NKB * NCOL * 32) return;
  int j    = idx & 7;
  int slot = (idx >> 3) & 3;
  int col  = (idx >> 5) % NCOL;
  int kb   = idx / (NCOL * 32);
  int kg   = slot ^ ((col >> 1) & 3);
  int k    = kb * 32 + kg * 8 + j;
  int seg  = k / KSEG;
  int kl   = k - seg * KSEG;
  int g    = col / KSEG;
  int h    = col - g * KSEG;
  float v = 0.0f;
  if (kl < SDIM && h < HDIM) {
    const float* src = (seg == 0) ? w_in : (seg == 1) ? w_out
                     : (seg == 2) ? u_in : u_out;
    v = src[(g * SDIM + kl) * HDIM + h];
  }
  wblk[idx] = (_Float16)v;
}

// Fused GEMM + gates + elementwise. 96 rows/block, 12 waves:
// wave = (rgrp 0..2, gate 0..3); per wave 32 rows x 160 cols, acc[2][10] f32x4.
// Depth-2 pipeline, 3 LDS buffers, counted-vmcnt barriers (no full drain).
__global__ __launch_bounds__(NTHREADS) void lstm_fused_kernel(
    const float* __restrict__ s_in, const float* __restrict__ s_out,
    const float* __restrict__ h_in, const float* __restrict__ h_out,
    const float* __restrict__ last_c, const float* __restrict__ bias,
    const _Float16* __restrict__ wblk,
    float* __restrict__ out_hid, float* __restrict__ out_cell) {
  __shared__ __align__(16) char lds[3 * BUFBYTES];  // 141312 B

  const int tid  = threadIdx.x;
  const int lane = tid & 63;
  const int l15  = lane & 15;
  const int kgrp = lane >> 4;
  const int wid  = tid >> 6;     // 0..11
  const int rgrp = wid >> 2;     // 0..2
  const int gate = wid & 3;      // 0..3
  const int row0 = blockIdx.x * BM;

  const float* segp[4] = {s_in, s_out, h_in, h_out};

  floatx4 acc[2][10] = {};

  // A staging assignment: thread -> row = tid>>3 (0..95), octet o = tid&7
  const int a_row  = tid >> 3;
  const int a_o    = tid & 7;
  const long n_a   = (long)row0 + a_row;
  const bool a_ok  = (n_a < NROWS);
  // A LDS: row*64B, 4 slots of 16B; slot s holds k-chunk (s ^ (row&3))
  const int a_off  = a_row * 64 + (((a_o >> 1) ^ (a_row & 3)) * 16) + (a_o & 1) * 8;

  char* buf0 = lds;
  char* buf1 = lds + BUFBYTES;
  char* buf2 = lds + 2 * BUFBYTES;

  auto stageB = [&](int kb, char* buf) {
    const char* g = (const char*)wblk + (size_t)kb * BSLICE;
    gload_lds16(g + (size_t)tid * 16,          buf + tid * 16);
    gload_lds16(g + (size_t)(tid + 768) * 16,  buf + (tid + 768) * 16);
    gload_lds16(g + (size_t)(tid + 1536) * 16, buf + (tid + 1536) * 16);
    if (tid < 256)
      gload_lds16(g + (size_t)(tid + 2304) * 16, buf + (tid + 2304) * 16);
  };
  auto loadA = [&](int kb, float& v0, float& v1, float& v2, float& v3) {
    v0 = v1 = v2 = v3 = 0.f;
    const int seg = kb / 5;
    const int kls = (kb % 5) * 32 + a_o * 4;
    if (a_ok && kls < SDIM) {
      const float* p = segp[seg] + (size_t)n_a * SDIM + kls;
      float2 q0 = *(const float2*)p;
      v0 = q0.x; v1 = q0.y;
      if (kls + 3 < SDIM) {
        float2 q1 = *(const float2*)(p + 2);
        v2 = q1.x; v3 = q1.y;
      }
    }
  };
  auto commitA = [&](char* buf, float v0, float v1, float v2, float v3) {
    union { _Float16 h[4]; uint2 u; } pk;
    pk.h[0] = (_Float16)v0; pk.h[1] = (_Float16)v1;
    pk.h[2] = (_Float16)v2; pk.h[3] = (_Float16)v3;
    *(uint2*)(buf + BSLICE + a_off) = pk.u;
  };
  auto compute = [&](const char* bc) {
    const char* aB = bc + BSLICE;
    const int r0 = rgrp * 32 + l15;
    half8 af0 = *(const half8*)(aB + r0 * 64 + ((kgrp ^ (r0 & 3)) * 16));
    const int r1 = r0 + 16;
    half8 af1 = *(const half8*)(aB + r1 * 64 + ((kgrp ^ (r1 & 3)) * 16));
#pragma unroll
    for (int ct = 0; ct < 10; ++ct) {
      int col = gate * 160 + ct * 16 + l15;
      half8 bf = *(const half8*)(bc + col * 64 + ((kgrp ^ ((col >> 1) & 3)) * 16));
      acc[0][ct] = __builtin_amdgcn_mfma_f32_16x16x32_f16(af0, bf, acc[0][ct], 0, 0, 0);
      acc[1][ct] = __builtin_amdgcn_mfma_f32_16x16x32_f16(af1, bf, acc[1][ct], 0, 0, 0);
    }
  };

  // ---- prologue: stage tiles 0 and 1 ----
  float an0 = 0.f, an1 = 0.f, an2 = 0.f, an3 = 0.f;  // A(t+1) raw
  {
    float a0, a1, a2, a3;
    stageB(0, buf0); loadA(0, a0, a1, a2, a3);
    stageB(1, buf1); loadA(1, an0, an1, an2, an3);
    commitA(buf0, a0, a1, a2, a3);
    if (wid < 4) KBAR(6); else KBAR(5);
  }

  char* bc = buf0;  // compute tile t
  char* bn = buf1;  // tile t+1 (A commit target)
  char* bs = buf2;  // staging target tile t+2
#pragma unroll 1
  for (int t = 0; t < NKB; ++t) {
    float av0 = 0.f, av1 = 0.f, av2 = 0.f, av3 = 0.f;
    const bool has2 = (t + 2 < NKB);
    if (has2) {
      stageB(t + 2, bs);                 // gload_lds, in flight across barrier
      loadA(t + 2, av0, av1, av2, av3);  // global->reg, consumed next iter
    }
    if (t + 1 < NKB) commitA(bn, an0, an1, an2, an3);  // cvt+ds_write A(t+1)
    compute(bc);
    an0 = av0; an1 = av1; an2 = av2; an3 = av3;
    if (has2) { if (wid < 4) KBAR(6); else KBAR(5); }
    else      { KBAR(0); }
    char* tmp = bc; bc = bn; bn = bs; bs = tmp;
  }

  // ---- epilogue: 3 slices of 32 rows; gates exchanged via f16 LDS overlay ----
  float bfrag[10];
#pragma unroll
  for (int ct = 0; ct < 10; ++ct) {
    int h = ct * 16 + l15;
    bfrag[ct] = (h < HDIM) ? bias[gate * HDIM + h] : 0.f;
  }
  _Float16* epi = (_Float16*)lds;  // 32 * 648 * 2B = 41472 B
  for (int s = 0; s < 3; ++s) {
    if (s) __syncthreads();
    if (rgrp == s) {
#pragma unroll
      for (int mt = 0; mt < 2; ++mt) {
#pragma unroll
        for (int ct = 0; ct < 10; ++ct) {
          int colb = gate * 160 + ct * 16 + l15;
#pragma unroll
          for (int i = 0; i < 4; ++i) {
            // C/D layout: col = lane&15, row = (lane>>4)*4 + i
            int rl = mt * 16 + kgrp * 4 + i;
            float gv = fsig(acc[mt][ct][i] + bfrag[ct]);
            epi[rl * EPI_STRIDE + colb] = (_Float16)gv;
          }
        }
      }
    }
    __syncthreads();
    // consume: gates[0]=input, [1]=output, [2]=forget, [3]=update
#pragma unroll
    for (int it = 0; it < 4; ++it) {
      int idx = tid + it * NTHREADS;
      if (idx < 32 * 75) {
        int row = idx / 75;
        int h2  = idx - row * 75;
        long n = (long)row0 + s * 32 + row;
        if (n < NROWS) {
          int h = h2 * 2;
          const _Float16* er = epi + row * EPI_STRIDE + h;
          half2v gi = *(const half2v*)(er + 0 * 160);
          half2v go = *(const half2v*)(er + 1 * 160);
          half2v gf = *(const half2v*)(er + 2 * 160);
          half2v gu = *(const half2v*)(er + 3 * 160);
          float2 lc = *(const float2*)(last_c + n * HDIM + h);
          float c0 = (float)gf[0] * lc.x + (float)gu[0] * (float)gi[0];
          float c1 = (float)gf[1] * lc.y + (float)gu[1] * (float)gi[1];
          float hd0 = (float)go[0] * ftanh(c0);
          float hd1 = (float)go[1] * ftanh(c1);
          *(float2*)(out_hid  + n * HDIM + h) = make_float2(hd0, hd1);
          *(float2*)(out_cell + n * HDIM + h) = make_float2(c0, c1);
        }
      }
    }
  }
}

extern "C" void kernel_launch(void* const* d_in, const int* in_sizes, int n_in,
                              void* d_out, int out_size, void* d_ws, size_t ws_size,
                              hipStream_t stream) {
  const float* s_in   = (const float*)d_in[0];
  const float* s_out  = (const float*)d_in[1];
  const float* h_in   = (const float*)d_in[2];
  const float* h_out  = (const float*)d_in[3];
  const float* last_c = (const float*)d_in[4];
  const float* w_in   = (const float*)d_in[5];
  const float* w_out  = (const float*)d_in[6];
  const float* u_in   = (const float*)d_in[7];
  const float* u_out  = (const float*)d_in[8];
  const float* b      = (const float*)d_in[9];

  _Float16* wblk = (_Float16*)d_ws;  // needs 819200 B

  pack_w_kernel<<<(NKB * NCOL * 32 + 255) / 256, 256, 0, stream>>>(
      w_in, w_out, u_in, u_out, wblk);

  float* out_hid  = (float*)d_out;
  float* out_cell = out_hid + (size_t)NROWS * HDIM;

  lstm_fused_kernel<<<(NROWS + BM - 1) / BM, NTHREADS, 0, stream>>>(
      s_in, s_out, h_in, h_out, last_c, b, wblk, out_hid, out_cell);
}

// Round 4
// 251.472 us; speedup vs baseline: 1.0140x; 1.0140x over previous
//
#include <hip/hip_runtime.h>
#include <stdint.h>

#define NROWS 100000
#define SDIM 150
#define HDIM 150
#define KSEG 160      // per-segment K, padded 150->160
#define NKB 20        // K-steps of 32 (total K = 640)
#define NCOL 640      // 4 gates * 160 padded cols
#define BM 128
#define NTHREADS 512
#define BSLICE 40960               // B bytes per K-step slice (640 cols * 32 k * 2B)
#define ASLICE 8192                // A f16 bytes per K-step (128 rows * 64B)
#define BUFBYTES (BSLICE + ASLICE) // 49152
#define EPI_STRIDE 656             // f16 elems per epilogue row (1312B: kgrp -> +8 banks)

using half8  = __attribute__((ext_vector_type(8))) _Float16;
using half2v = __attribute__((ext_vector_type(2))) _Float16;
using floatx4 = __attribute__((ext_vector_type(4))) float;

__device__ __forceinline__ float fsig(float x) {
  return __builtin_amdgcn_rcpf(1.0f + __expf(-x));
}
__device__ __forceinline__ float ftanh(float x) {
  return 2.0f * __builtin_amdgcn_rcpf(1.0f + __expf(-2.0f * x)) - 1.0f;
}

__device__ __forceinline__ void gload_lds16(const void* g, void* l) {
  __builtin_amdgcn_global_load_lds(
      (const __attribute__((address_space(1))) void*)g,
      (__attribute__((address_space(3))) void*)l, 16, 0, 0);
}

// Barrier with counted vmcnt: drains loads issued in PREVIOUS iters only;
// current iter's staging (7 loads/thread) stays in flight across the barrier.
#define KBAR(VM)                                              \
  do {                                                        \
    asm volatile("s_waitcnt vmcnt(" #VM ")" ::: "memory");    \
    asm volatile("s_waitcnt lgkmcnt(0)" ::: "memory");        \
    __builtin_amdgcn_s_barrier();                             \
    asm volatile("" ::: "memory");                            \
  } while (0)

// Pack W = [w_in; w_out; u_in; u_out] (600x600 fp32) into f16, K-blocked,
// XOR-swizzled: element (col,k) at byte
//   kb*BSLICE + col*64 + slot*16 + (k&7)*2,  kb=k>>5, slot=((k>>3)&3)^((col>>1)&3)
__global__ void pack_w_kernel(const float* __restrict__ w_in,
                              const float* __restrict__ w_out,
                              const float* __restrict__ u_in,
                              const float* __restrict__ u_out,
                              _Float16* __restrict__ wblk) {
  int idx = blockIdx.x * 256 + threadIdx.x;
  if (idx >= NKB * NCOL * 32) return;
  int j    = idx & 7;
  int slot = (idx >> 3) & 3;
  int col  = (idx >> 5) % NCOL;
  int kb   = idx / (NCOL * 32);
  int kg   = slot ^ ((col >> 1) & 3);
  int k    = kb * 32 + kg * 8 + j;
  int seg  = k / KSEG;
  int kl   = k - seg * KSEG;
  int g    = col / KSEG;
  int h    = col - g * KSEG;
  float v = 0.0f;
  if (kl < SDIM && h < HDIM) {
    const float* src = (seg == 0) ? w_in : (seg == 1) ? w_out
                     : (seg == 2) ? u_in : u_out;
    v = src[(g * SDIM + kl) * HDIM + h];
  }
  wblk[idx] = (_Float16)v;
}

// Fused GEMM + gates + elementwise. 128 rows/block, 8 waves (512 thr).
// Wave wid owns ALL 128 rows x cols [wid*80, wid*80+80): B read once per
// K-step (no duplication), acc[8][5] f32x4 = 160 regs/lane.
// Depth-2 pipeline, 3 LDS buffers, counted-vmcnt barriers.
__global__ __launch_bounds__(NTHREADS, 2) void lstm_fused_kernel(
    const float* __restrict__ s_in, const float* __restrict__ s_out,
    const float* __restrict__ h_in, const float* __restrict__ h_out,
    const float* __restrict__ last_c, const float* __restrict__ bias,
    const _Float16* __restrict__ wblk,
    float* __restrict__ out_hid, float* __restrict__ out_cell) {
  __shared__ __align__(16) char lds[3 * BUFBYTES];  // 147456 B

  const int tid  = threadIdx.x;
  const int lane = tid & 63;
  const int l15  = lane & 15;
  const int kgrp = lane >> 4;
  const int wid  = tid >> 6;      // 0..7
  const int gate = wid >> 1;      // 0..3
  const int cb   = wid * 80;      // column base (within 640)
  const int row0 = blockIdx.x * BM;

  const float* segp[4] = {s_in, s_out, h_in, h_out};

  floatx4 acc[8][5] = {};

  // bias fragment (C/D col = lane&15); col within gate = (wid&1)*80 + n*16 + l15
  float bfrag[5];
#pragma unroll
  for (int n = 0; n < 5; ++n) {
    int h = (wid & 1) * 80 + n * 16 + l15;
    bfrag[n] = (h < HDIM) ? bias[gate * HDIM + h] : 0.f;
  }

  // A staging: thread -> row = tid>>2 (0..127), quarter q = tid&3 (16B chunk)
  const int a_row = tid >> 2;
  const int a_q   = tid & 3;
  const long n_a  = (long)row0 + a_row;
  const bool a_ok = (n_a < NROWS);
  // A LDS: row*64B; chunk c stored at slot (c ^ ((row>>1)&3)) -- conflict-free read
  const int a_off = a_row * 64 + ((a_q ^ ((a_row >> 1) & 3)) * 16);

  char* buf0 = lds;
  char* buf1 = lds + BUFBYTES;
  char* buf2 = lds + 2 * BUFBYTES;

  auto stageB = [&](int kb, char* buf) {
    const char* g = (const char*)wblk + (size_t)kb * BSLICE + tid * 16;
    char* d = buf + tid * 16;
#pragma unroll
    for (int i = 0; i < 5; ++i)
      gload_lds16(g + i * 8192, d + i * 8192);
  };
  auto loadA = [&](int kb, float4& lo, float4& hi) {
    lo = make_float4(0.f, 0.f, 0.f, 0.f);
    hi = make_float4(0.f, 0.f, 0.f, 0.f);
    const int seg = kb / 5;
    const int kls = (kb % 5) * 32 + a_q * 8;
    if (a_ok && kls < SDIM) {
      const float* p = segp[seg] + (size_t)n_a * SDIM + kls;
      if (kls + 7 < SDIM) {
        lo = *(const float4*)p;
        hi = *(const float4*)(p + 4);
      } else {
        float t[8] = {0.f, 0.f, 0.f, 0.f, 0.f, 0.f, 0.f, 0.f};
#pragma unroll
        for (int i = 0; i < 8; ++i)
          if (kls + i < SDIM) t[i] = p[i];
        lo = make_float4(t[0], t[1], t[2], t[3]);
        hi = make_float4(t[4], t[5], t[6], t[7]);
      }
    }
  };
  auto commitA = [&](char* buf, float4 lo, float4 hi) {
    union { _Float16 h[8]; uint4 u; } pk;
    pk.h[0] = (_Float16)lo.x; pk.h[1] = (_Float16)lo.y;
    pk.h[2] = (_Float16)lo.z; pk.h[3] = (_Float16)lo.w;
    pk.h[4] = (_Float16)hi.x; pk.h[5] = (_Float16)hi.y;
    pk.h[6] = (_Float16)hi.z; pk.h[7] = (_Float16)hi.w;
    *(uint4*)(buf + BSLICE + a_off) = pk.u;
  };
  auto compute = [&](const char* bufc) {
    const char* aB = bufc + BSLICE;
    half8 bf[5];
#pragma unroll
    for (int n = 0; n < 5; ++n) {
      int col = cb + n * 16 + l15;
      bf[n] = *(const half8*)(bufc + col * 64 + ((kgrp ^ ((col >> 1) & 3)) * 16));
    }
#pragma unroll
    for (int mt = 0; mt < 8; ++mt) {
      int r = mt * 16 + l15;
      half8 af = *(const half8*)(aB + r * 64 + ((kgrp ^ ((r >> 1) & 3)) * 16));
#pragma unroll
      for (int n = 0; n < 5; ++n)
        acc[mt][n] = __builtin_amdgcn_mfma_f32_16x16x32_f16(af, bf[n], acc[mt][n], 0, 0, 0);
    }
  };

  // ---- prologue: stage tiles 0 and 1 ----
  float4 anl, anh;  // A(t+1) raw
  {
    float4 a0l, a0h;
    stageB(0, buf0); loadA(0, a0l, a0h);
    stageB(1, buf1); loadA(1, anl, anh);
    commitA(buf0, a0l, a0h);
    KBAR(7);  // outstanding: B1(5) + A1(2)
  }

  char* bc = buf0;  // compute tile t
  char* bn = buf1;  // tile t+1 (A commit target)
  char* bs = buf2;  // staging target tile t+2
#pragma unroll 1
  for (int t = 0; t < NKB; ++t) {
    float4 avl, avh;
    const bool has2 = (t + 2 < NKB);
    if (has2) {
      stageB(t + 2, bs);         // in flight across the barrier
      loadA(t + 2, avl, avh);    // global->reg, consumed next iter
    }
    if (t + 1 < NKB) commitA(bn, anl, anh);  // cvt + ds_write A(t+1)
    compute(bc);
    anl = avl; anh = avh;
    if (has2) KBAR(7); else KBAR(0);
    char* tmp = bc; bc = bn; bn = bs; bs = tmp;
  }

  // ---- epilogue: 4 slices of 32 rows; gate exchange via f16 LDS overlay ----
  _Float16* epi = (_Float16*)lds;  // 32 * 656 * 2B = 41984 B
#pragma unroll
  for (int s = 0; s < 4; ++s) {
    if (s) __syncthreads();  // previous slice consumed
#pragma unroll
    for (int mt2 = 0; mt2 < 2; ++mt2) {
      const int mt = 2 * s + mt2;
#pragma unroll
      for (int n = 0; n < 5; ++n) {
        int col = cb + n * 16 + l15;
#pragma unroll
        for (int i = 0; i < 4; ++i) {
          // C/D layout: col = lane&15, row = (lane>>4)*4 + i
          int rl = mt2 * 16 + kgrp * 4 + i;
          float gv = fsig(acc[mt][n][i] + bfrag[n]);
          epi[rl * EPI_STRIDE + col] = (_Float16)gv;
        }
      }
    }
    __syncthreads();
    // consume: gates[0]=input, [1]=output, [2]=forget, [3]=update
#pragma unroll
    for (int it = 0; it < 5; ++it) {
      int idx = tid + it * NTHREADS;
      if (idx < 32 * 75) {
        int row = idx / 75;
        int h2  = idx - row * 75;
        long n = (long)row0 + s * 32 + row;
        if (n < NROWS) {
          int h = h2 * 2;
          const _Float16* er = epi + row * EPI_STRIDE + h;
          half2v gi = *(const half2v*)(er + 0 * 160);
          half2v go = *(const half2v*)(er + 1 * 160);
          half2v gf = *(const half2v*)(er + 2 * 160);
          half2v gu = *(const half2v*)(er + 3 * 160);
          float2 lc = *(const float2*)(last_c + n * HDIM + h);
          float c0 = (float)gf[0] * lc.x + (float)gu[0] * (float)gi[0];
          float c1 = (float)gf[1] * lc.y + (float)gu[1] * (float)gi[1];
          float hd0 = (float)go[0] * ftanh(c0);
          float hd1 = (float)go[1] * ftanh(c1);
          *(float2*)(out_hid  + n * HDIM + h) = make_float2(hd0, hd1);
          *(float2*)(out_cell + n * HDIM + h) = make_float2(c0, c1);
        }
      }
    }
  }
}

extern "C" void kernel_launch(void* const* d_in, const int* in_sizes, int n_in,
                              void* d_out, int out_size, void* d_ws, size_t ws_size,
                              hipStream_t stream) {
  const float* s_in   = (const float*)d_in[0];
  const float* s_out  = (const float*)d_in[1];
  const float* h_in   = (const float*)d_in[2];
  const float* h_out  = (const float*)d_in[3];
  const float* last_c = (const float*)d_in[4];
  const float* w_in   = (const float*)d_in[5];
  const float* w_out  = (const float*)d_in[6];
  const float* u_in   = (const float*)d_in[7];
  const float* u_out  = (const float*)d_in[8];
  const float* b      = (const float*)d_in[9];

  _Float16* wblk = (_Float16*)d_ws;  // needs 819200 B

  pack_w_kernel<<<(NKB * NCOL * 32 + 255) / 256, 256, 0, stream>>>(
      w_in, w_out, u_in, u_out, wblk);

  float* out_hid  = (float*)d_out;
  float* out_cell = out_hid + (size_t)NROWS * HDIM;

  lstm_fused_kernel<<<(NROWS + BM - 1) / BM, NTHREADS, 0, stream>>>(
      s_in, s_out, h_in, h_out, last_c, b, wblk, out_hid, out_cell);
}

// Round 5
// 222.883 us; speedup vs baseline: 1.1440x; 1.1283x over previous
//
#include <hip/hip_runtime.h>
#include <stdint.h>

#define NROWS 100000
#define SDIM 150
#define HDIM 150
#define KSEG 160      // per-segment K, padded 150->160
#define NKB 20        // K-steps of 32 (total K = 640)
#define NCOL 640      // 4 gates * 160 padded cols
#define BM 128
#define NTHREADS 512
#define BSLICE 40960               // B bytes per K-step slice (640 cols * 32 k * 2B)
#define ASLICE 8192                // A f16 bytes per K-step (128 rows * 64B)
#define BUFBYTES (BSLICE + ASLICE) // 49152
#define EPI_STRIDE 656             // f16 elems per epilogue row

using half8  = __attribute__((ext_vector_type(8))) _Float16;
using half2v = __attribute__((ext_vector_type(2))) _Float16;
using floatx4 = __attribute__((ext_vector_type(4))) float;

__device__ __forceinline__ float fsig(float x) {
  return __builtin_amdgcn_rcpf(1.0f + __expf(-x));
}
__device__ __forceinline__ float ftanh(float x) {
  return 2.0f * __builtin_amdgcn_rcpf(1.0f + __expf(-2.0f * x)) - 1.0f;
}

// Barrier: ds-visibility only. NO vmcnt here — global loads stay in flight;
// the compiler inserts precise per-register vmcnt waits at their uses.
#define LBAR()                                                \
  do {                                                        \
    asm volatile("s_waitcnt lgkmcnt(0)" ::: "memory");        \
    __builtin_amdgcn_s_barrier();                             \
    asm volatile("" ::: "memory");                            \
  } while (0)

// Pack W = [w_in; w_out; u_in; u_out] (600x600 fp32) into f16, K-blocked,
// XOR-swizzled: element (col,k) at byte
//   kb*BSLICE + col*64 + slot*16 + (k&7)*2,  kb=k>>5, slot=((k>>3)&3)^((col>>1)&3)
__global__ void pack_w_kernel(const float* __restrict__ w_in,
                              const float* __restrict__ w_out,
                              const float* __restrict__ u_in,
                              const float* __restrict__ u_out,
                              _Float16* __restrict__ wblk) {
  int idx = blockIdx.x * 256 + threadIdx.x;
  if (idx >= NKB * NCOL * 32) return;
  int j    = idx & 7;
  int slot = (idx >> 3) & 3;
  int col  = (idx >> 5) % NCOL;
  int kb   = idx / (NCOL * 32);
  int kg   = slot ^ ((col >> 1) & 3);
  int k    = kb * 32 + kg * 8 + j;
  int seg  = k / KSEG;
  int kl   = k - seg * KSEG;
  int g    = col / KSEG;
  int h    = col - g * KSEG;
  float v = 0.0f;
  if (kl < SDIM && h < HDIM) {
    const float* src = (seg == 0) ? w_in : (seg == 1) ? w_out
                     : (seg == 2) ? u_in : u_out;
    v = src[(g * SDIM + kl) * HDIM + h];
  }
  wblk[idx] = (_Float16)v;
}

// Fused GEMM + gates + elementwise. 128 rows/block, 8 waves (512 thr).
// Wave wid owns ALL 128 rows x cols [wid*80, wid*80+80): acc[8][5] f32x4.
// REGISTER-STAGED pipeline: global->reg (B 5xuint4, A 2xfloat4) -> ds_write.
// One lgkm-only barrier per K-step; global loads remain in flight across it.
__global__ __launch_bounds__(NTHREADS) void lstm_fused_kernel(
    const float* __restrict__ s_in, const float* __restrict__ s_out,
    const float* __restrict__ h_in, const float* __restrict__ h_out,
    const float* __restrict__ last_c, const float* __restrict__ bias,
    const _Float16* __restrict__ wblk,
    float* __restrict__ out_hid, float* __restrict__ out_cell) {
  __shared__ __align__(16) char lds[2 * BUFBYTES];  // 98304 B

  const int tid  = threadIdx.x;
  const int lane = tid & 63;
  const int l15  = lane & 15;
  const int kgrp = lane >> 4;
  const int wid  = tid >> 6;      // 0..7
  const int gate = wid >> 1;      // 0..3
  const int cb   = wid * 80;      // column base (within 640)
  const int row0 = blockIdx.x * BM;

  const float* segp[4] = {s_in, s_out, h_in, h_out};

  floatx4 acc[8][5] = {};

  float bfrag[5];
#pragma unroll
  for (int n = 0; n < 5; ++n) {
    int h = (wid & 1) * 80 + n * 16 + l15;
    bfrag[n] = (h < HDIM) ? bias[gate * HDIM + h] : 0.f;
  }

  // A staging: thread -> row = tid>>2 (0..127), quarter q = tid&3 (16B chunk)
  const int a_row = tid >> 2;
  const int a_q   = tid & 3;
  const long n_a  = (long)row0 + a_row;
  const bool a_ok = (n_a < NROWS);
  const int a_off = a_row * 64 + ((a_q ^ ((a_row >> 1) & 3)) * 16);

  char* cur = lds;
  char* nxt = lds + BUFBYTES;

  // ---- staging registers ----
  uint4 bR0, bR1, bR2, bR3, bR4;          // B tile t+1 (5 x 16B)
  float4 aE_lo, aE_hi, aO_lo, aO_hi;      // A even/odd sets (2-deep)

  auto loadB = [&](int kb) {
    const char* g = (const char*)wblk + (size_t)kb * BSLICE + tid * 16;
    bR0 = *(const uint4*)(g);
    bR1 = *(const uint4*)(g + 8192);
    bR2 = *(const uint4*)(g + 16384);
    bR3 = *(const uint4*)(g + 24576);
    bR4 = *(const uint4*)(g + 32768);
  };
  auto loadA = [&](int kb, float4& lo, float4& hi) {
    lo = make_float4(0.f, 0.f, 0.f, 0.f);
    hi = make_float4(0.f, 0.f, 0.f, 0.f);
    const int seg = kb / 5;
    const int kls = (kb % 5) * 32 + a_q * 8;
    if (a_ok && kls < SDIM) {
      const float* p = segp[seg] + (size_t)n_a * SDIM + kls;
      if (kls + 7 < SDIM) {
        lo = *(const float4*)p;
        hi = *(const float4*)(p + 4);
      } else {
        float t[8] = {0.f, 0.f, 0.f, 0.f, 0.f, 0.f, 0.f, 0.f};
#pragma unroll
        for (int i = 0; i < 8; ++i)
          if (kls + i < SDIM) t[i] = p[i];
        lo = make_float4(t[0], t[1], t[2], t[3]);
        hi = make_float4(t[4], t[5], t[6], t[7]);
      }
    }
  };
  auto writeB = [&](char* buf) {
    char* d = buf + tid * 16;
    *(uint4*)(d)         = bR0;
    *(uint4*)(d + 8192)  = bR1;
    *(uint4*)(d + 16384) = bR2;
    *(uint4*)(d + 24576) = bR3;
    *(uint4*)(d + 32768) = bR4;
  };
  auto commitA = [&](char* buf, const float4& lo, const float4& hi) {
    union { _Float16 h[8]; uint4 u; } pk;
    pk.h[0] = (_Float16)lo.x; pk.h[1] = (_Float16)lo.y;
    pk.h[2] = (_Float16)lo.z; pk.h[3] = (_Float16)lo.w;
    pk.h[4] = (_Float16)hi.x; pk.h[5] = (_Float16)hi.y;
    pk.h[6] = (_Float16)hi.z; pk.h[7] = (_Float16)hi.w;
    *(uint4*)(buf + BSLICE + a_off) = pk.u;
  };
  auto compute = [&](const char* bufc) {
    const char* aB = bufc + BSLICE;
    half8 bf[5];
#pragma unroll
    for (int n = 0; n < 5; ++n) {
      int col = cb + n * 16 + l15;
      bf[n] = *(const half8*)(bufc + col * 64 + ((kgrp ^ ((col >> 1) & 3)) * 16));
    }
    __builtin_amdgcn_s_setprio(1);
#pragma unroll
    for (int mt = 0; mt < 8; ++mt) {
      int r = mt * 16 + l15;
      half8 af = *(const half8*)(aB + r * 64 + ((kgrp ^ ((r >> 1) & 3)) * 16));
#pragma unroll
      for (int n = 0; n < 5; ++n)
        acc[mt][n] = __builtin_amdgcn_mfma_f32_16x16x32_f16(af, bf[n], acc[mt][n], 0, 0, 0);
    }
    __builtin_amdgcn_s_setprio(0);
  };

  // ---- prologue ----
  // set[k&1] holds A tile k. Load A0->E, A1->O, B0; publish tile0 into cur;
  // load A2->E (2-deep), B1 (1-deep); barrier.
  loadA(0, aE_lo, aE_hi);
  loadA(1, aO_lo, aO_hi);
  loadB(0);
  writeB(cur);                 // compiler waits precisely on bR* here
  commitA(cur, aE_lo, aE_hi);  // and on aE here
  loadA(2, aE_lo, aE_hi);
  loadB(1);
  LBAR();

  // ---- K-loop: manual 2x unroll so A-set parity is static (NKB even) ----
  auto body = [&](int t, float4& pubLo, float4& pubHi) {
    // publish tile t+1 (regs loaded 1-2 iters ago) into nxt
    if (t + 1 < NKB) {
      writeB(nxt);
      commitA(nxt, pubLo, pubHi);
    }
    // refill: B(t+2) 1-deep, A(t+3) 2-deep into the set just published
    if (t + 2 < NKB) loadB(t + 2);
    if (t + 3 < NKB) loadA(t + 3, pubLo, pubHi);
    compute(cur);
    LBAR();
    char* tmp = cur; cur = nxt; nxt = tmp;
  };
#pragma unroll 1
  for (int t = 0; t < NKB; t += 2) {
    body(t,     aO_lo, aO_hi);  // t even: publishes tile t+1 (odd set)
    body(t + 1, aE_lo, aE_hi);  // t odd:  publishes tile t+2 (even set)
  }

  // ---- epilogue: 4 slices of 32 rows; gate exchange via f16 LDS overlay ----
  _Float16* epi = (_Float16*)lds;  // 32 * 656 * 2B = 41984 B
#pragma unroll
  for (int s = 0; s < 4; ++s) {
    if (s) __syncthreads();  // previous slice consumed
#pragma unroll
    for (int mt2 = 0; mt2 < 2; ++mt2) {
      const int mt = 2 * s + mt2;
#pragma unroll
      for (int n = 0; n < 5; ++n) {
        int col = cb + n * 16 + l15;
#pragma unroll
        for (int i = 0; i < 4; ++i) {
          // C/D layout: col = lane&15, row = (lane>>4)*4 + i
          int rl = mt2 * 16 + kgrp * 4 + i;
          float gv = fsig(acc[mt][n][i] + bfrag[n]);
          epi[rl * EPI_STRIDE + col] = (_Float16)gv;
        }
      }
    }
    __syncthreads();
    // consume: gates[0]=input, [1]=output, [2]=forget, [3]=update
#pragma unroll
    for (int it = 0; it < 5; ++it) {
      int idx = tid + it * NTHREADS;
      if (idx < 32 * 75) {
        int row = idx / 75;
        int h2  = idx - row * 75;
        long n = (long)row0 + s * 32 + row;
        if (n < NROWS) {
          int h = h2 * 2;
          const _Float16* er = epi + row * EPI_STRIDE + h;
          half2v gi = *(const half2v*)(er + 0 * 160);
          half2v go = *(const half2v*)(er + 1 * 160);
          half2v gf = *(const half2v*)(er + 2 * 160);
          half2v gu = *(const half2v*)(er + 3 * 160);
          float2 lc = *(const float2*)(last_c + n * HDIM + h);
          float c0 = (float)gf[0] * lc.x + (float)gu[0] * (float)gi[0];
          float c1 = (float)gf[1] * lc.y + (float)gu[1] * (float)gi[1];
          float hd0 = (float)go[0] * ftanh(c0);
          float hd1 = (float)go[1] * ftanh(c1);
          *(float2*)(out_hid  + n * HDIM + h) = make_float2(hd0, hd1);
          *(float2*)(out_cell + n * HDIM + h) = make_float2(c0, c1);
        }
      }
    }
  }
}

extern "C" void kernel_launch(void* const* d_in, const int* in_sizes, int n_in,
                              void* d_out, int out_size, void* d_ws, size_t ws_size,
                              hipStream_t stream) {
  const float* s_in   = (const float*)d_in[0];
  const float* s_out  = (const float*)d_in[1];
  const float* h_in   = (const float*)d_in[2];
  const float* h_out  = (const float*)d_in[3];
  const float* last_c = (const float*)d_in[4];
  const float* w_in   = (const float*)d_in[5];
  const float* w_out  = (const float*)d_in[6];
  const float* u_in   = (const float*)d_in[7];
  const float* u_out  = (const float*)d_in[8];
  const float* b      = (const float*)d_in[9];

  _Float16* wblk = (_Float16*)d_ws;  // needs 819200 B

  pack_w_kernel<<<(NKB * NCOL * 32 + 255) / 256, 256, 0, stream>>>(
      w_in, w_out, u_in, u_out, wblk);

  float* out_hid  = (float*)d_out;
  float* out_cell = out_hid + (size_t)NROWS * HDIM;

  lstm_fused_kernel<<<(NROWS + BM - 1) / BM, NTHREADS, 0, stream>>>(
      s_in, s_out, h_in, h_out, last_c, b, wblk, out_hid, out_cell);
}

// Round 6
// 222.807 us; speedup vs baseline: 1.1444x; 1.0003x over previous
//
#include <hip/hip_runtime.h>
#include <stdint.h>

#define NROWS 100000
#define SDIM 150
#define HDIM 150
#define NKB 20               // K-steps of 32 (total K = 640)
#define NCOLF 640            // full packed cols, h-major: col = h*4 + g
#define BN 320               // cols per block = 80 h-values x 4 gates
#define BM 64
#define NTHREADS 256
#define BSLICE_FULL 40960    // full-width B bytes per K-step (640*64)
#define BSTAGE 20480         // per-block B bytes per K-step (320*64)
#define ASTAGE 4096          // 64 rows * 64B
#define EPIW 328             // epi overlay stride in f16 (656B = 41*16, 16B-aligned rows)

using half8  = __attribute__((ext_vector_type(8))) _Float16;
using floatx4 = __attribute__((ext_vector_type(4))) float;

__device__ __forceinline__ float fsig(float x) {
  return __builtin_amdgcn_rcpf(1.0f + __expf(-x));
}
__device__ __forceinline__ float ftanh(float x) {
  return 2.0f * __builtin_amdgcn_rcpf(1.0f + __expf(-2.0f * x)) - 1.0f;
}

__device__ __forceinline__ void gload_lds16(const void* g, void* l) {
  __builtin_amdgcn_global_load_lds(
      (const __attribute__((address_space(1))) void*)g,
      (__attribute__((address_space(3))) void*)l, 16, 0, 0);
}

// Full barrier (staging visible): vm+lgkm drain. rA(t+1) is issued AFTER this,
// so the vm drain only covers the L2-resident B staging (~300cy, TLP-hidden).
#define BAR_FULL()                                            \
  do {                                                        \
    asm volatile("s_waitcnt vmcnt(0)" ::: "memory");          \
    asm volatile("s_waitcnt lgkmcnt(0)" ::: "memory");        \
    __builtin_amdgcn_s_barrier();                             \
    asm volatile("" ::: "memory");                            \
  } while (0)

// LDS-only barrier (reads of buffer done before overwrite): lgkm only —
// in-flight A global loads cross it freely.
#define BAR_LDS()                                             \
  do {                                                        \
    asm volatile("s_waitcnt lgkmcnt(0)" ::: "memory");        \
    __builtin_amdgcn_s_barrier();                             \
    asm volatile("" ::: "memory");                            \
  } while (0)

// Pack W = [w_in; w_out; u_in; u_out] (600x600 f32) into f16, K-blocked,
// h-major columns (col = h*4 + g), XOR-swizzled:
//   byte(col,k) = kb*BSLICE_FULL + col*64 + slot*16 + (k&7)*2
//   kb = k>>5, slot = ((k>>3)&3) ^ ((col>>1)&3)
// k = seg*160 + kl (seg selects w_in/w_out/u_in/u_out), zero-padded kl>=150, h>=150.
__global__ void pack_w_kernel(const float* __restrict__ w_in,
                              const float* __restrict__ w_out,
                              const float* __restrict__ u_in,
                              const float* __restrict__ u_out,
                              _Float16* __restrict__ wblk) {
  int idx = blockIdx.x * 256 + threadIdx.x;
  if (idx >= NKB * NCOLF * 32) return;
  int j    = idx & 7;
  int slot = (idx >> 3) & 3;
  int col  = (idx >> 5) % NCOLF;
  int kb   = idx / (NCOLF * 32);
  int kg   = slot ^ ((col >> 1) & 3);
  int k    = kb * 32 + kg * 8 + j;
  int seg  = k / 160;
  int kl   = k - seg * 160;
  int g    = col & 3;         // gate: 0=input 1=output 2=forget 3=update
  int h    = col >> 2;        // hidden index
  float v = 0.0f;
  if (kl < SDIM && h < HDIM) {
    const float* src = (seg == 0) ? w_in : (seg == 1) ? w_out
                     : (seg == 2) ? u_in : u_out;
    v = src[(g * SDIM + kl) * HDIM + h];
  }
  wblk[idx] = (_Float16)v;
}

// Fused GEMM + gates + elementwise. Block = 64 rows x 320 cols (80 h x 4 g),
// 4 waves; wave cgrp owns 64 rows x 80 cols: acc[4][5] f32x4 = 80 VGPR.
// Single-buffered 24.5KB LDS -> ~4 blocks/CU; TLP hides barrier drains.
__global__ __launch_bounds__(NTHREADS, 4) void lstm_fused_kernel(
    const float* __restrict__ s_in, const float* __restrict__ s_out,
    const float* __restrict__ h_in, const float* __restrict__ h_out,
    const float* __restrict__ last_c, const float* __restrict__ bias,
    const _Float16* __restrict__ wblk,
    float* __restrict__ out_hid, float* __restrict__ out_cell) {
  __shared__ __align__(16) char lds[BSTAGE + ASTAGE];  // 24576 B

  const int tid  = threadIdx.x;
  const int lane = tid & 63;
  const int l15  = lane & 15;
  const int kgrp = lane >> 4;
  const int cgrp = tid >> 6;          // wave 0..3: cols [cgrp*80, cgrp*80+80)
  const int rb   = blockIdx.x >> 1;
  const int cblk = blockIdx.x & 1;
  const int cb0  = cblk * BN;         // global col base (0 or 320)
  const int h0   = cblk * 80;         // global h base (0 or 80)
  const int row0 = rb * BM;

  const float* segp[4] = {s_in, s_out, h_in, h_out};

  floatx4 acc[4][5] = {};

  // bias fragment: global col = cb0 + cgrp*80 + n*16 + l15 -> (h = col>>2, g = col&3)
  float bfrag[5];
#pragma unroll
  for (int n = 0; n < 5; ++n) {
    int col = cb0 + cgrp * 80 + n * 16 + l15;
    int h = col >> 2, g = col & 3;
    bfrag[n] = (h < HDIM) ? bias[g * HDIM + h] : 0.f;
  }

  // A staging: thread -> row = tid>>2 (0..63), 16B k-chunk q = tid&3
  const int a_row = tid >> 2;
  const int a_q   = tid & 3;
  const long n_a  = (long)row0 + a_row;
  const bool a_ok = (n_a < NROWS);
  const int a_off = a_row * 64 + ((a_q ^ ((a_row >> 1) & 3)) * 16);

  char* ldsB = lds;
  char* ldsA = lds + BSTAGE;

  float4 rAlo, rAhi;  // A(t) raw f32, loaded one phase ahead

  auto loadA = [&](int kb) {
    rAlo = make_float4(0.f, 0.f, 0.f, 0.f);
    rAhi = make_float4(0.f, 0.f, 0.f, 0.f);
    const int seg = kb / 5;
    const int kls = (kb % 5) * 32 + a_q * 8;
    if (a_ok && kls < SDIM) {
      const float* p = segp[seg] + (size_t)n_a * SDIM + kls;
      if (kls + 7 < SDIM) {
        rAlo = *(const float4*)p;
        rAhi = *(const float4*)(p + 4);
      } else {
        float t[8] = {0.f, 0.f, 0.f, 0.f, 0.f, 0.f, 0.f, 0.f};
#pragma unroll
        for (int i = 0; i < 8; ++i)
          if (kls + i < SDIM) t[i] = p[i];
        rAlo = make_float4(t[0], t[1], t[2], t[3]);
        rAhi = make_float4(t[4], t[5], t[6], t[7]);
      }
    }
  };
  auto commitA = [&]() {  // cvt f32->f16, ds_write_b128
    union { _Float16 h[8]; uint4 u; } pk;
    pk.h[0] = (_Float16)rAlo.x; pk.h[1] = (_Float16)rAlo.y;
    pk.h[2] = (_Float16)rAlo.z; pk.h[3] = (_Float16)rAlo.w;
    pk.h[4] = (_Float16)rAhi.x; pk.h[5] = (_Float16)rAhi.y;
    pk.h[6] = (_Float16)rAhi.z; pk.h[7] = (_Float16)rAhi.w;
    *(uint4*)(ldsA + a_off) = pk.u;
  };
  auto stageB = [&](int kb) {  // contiguous 20480B chunk of the packed slice
    const char* g = (const char*)wblk + (size_t)kb * BSLICE_FULL + cb0 * 64 + tid * 16;
    char* d = ldsB + tid * 16;
#pragma unroll
    for (int i = 0; i < 5; ++i)
      gload_lds16(g + i * 4096, d + i * 4096);
  };
  auto compute = [&]() {
    half8 bf[5];
#pragma unroll
    for (int n = 0; n < 5; ++n) {
      int cl = cgrp * 80 + n * 16 + l15;  // local col; swizzle identical in local coords
      bf[n] = *(const half8*)(ldsB + cl * 64 + ((kgrp ^ ((cl >> 1) & 3)) * 16));
    }
    __builtin_amdgcn_s_setprio(1);
#pragma unroll
    for (int mt = 0; mt < 4; ++mt) {
      int r = mt * 16 + l15;
      half8 af = *(const half8*)(ldsA + r * 64 + ((kgrp ^ ((r >> 1) & 3)) * 16));
#pragma unroll
      for (int n = 0; n < 5; ++n)
        acc[mt][n] = __builtin_amdgcn_mfma_f32_16x16x32_f16(af, bf[n], acc[mt][n], 0, 0, 0);
    }
    __builtin_amdgcn_s_setprio(0);
  };

  // ---- K-loop: single-buffered, 2 barriers/step, 4 blocks/CU hide drains ----
  loadA(0);
#pragma unroll 1
  for (int t = 0; t < NKB; ++t) {
    stageB(t);        // global_load_lds (L2)
    commitA();        // waits rA vmcnt precisely; ds_write
    BAR_FULL();       // B + A visible in LDS
    if (t + 1 < NKB) loadA(t + 1);  // HBM latency hides under compute + barrier
    compute();
    BAR_LDS();        // LDS reads done; A-loads stay in flight
  }

  // ---- epilogue: two 32-row halves via f16 overlay on lds ----
  _Float16* epi = (_Float16*)lds;  // 32 * 328 * 2 = 20992 B
#pragma unroll
  for (int hh = 0; hh < 2; ++hh) {
    __syncthreads();  // prior phase's LDS use complete
#pragma unroll
    for (int mt2 = 0; mt2 < 2; ++mt2) {
      const int mt = hh * 2 + mt2;
#pragma unroll
      for (int n = 0; n < 5; ++n) {
        int cl = cgrp * 80 + n * 16 + l15;
#pragma unroll
        for (int i = 0; i < 4; ++i) {
          // C/D layout: col = lane&15, row = (lane>>4)*4 + i
          int rl = mt2 * 16 + kgrp * 4 + i;
          float gv = fsig(acc[mt][n][i] + bfrag[n]);
          epi[rl * EPIW + cl] = (_Float16)gv;
        }
      }
    }
    __syncthreads();
    // consume: per (row, h-pair): 8 f16 = [gi,go,gf,gu]@h, [gi,go,gf,gu]@h+1
#pragma unroll
    for (int it = 0; it < 5; ++it) {
      int idx = tid + it * NTHREADS;     // 32 rows * 40 pairs = 1280 = 5*256
      int row = idx / 40;
      int pr  = idx - row * 40;
      long n = (long)row0 + hh * 32 + row;
      int hg = h0 + pr * 2;
      if (n < NROWS && hg < HDIM) {
        union { uint4 u; _Float16 f[8]; } gg;
        gg.u = *(const uint4*)(epi + row * EPIW + pr * 8);
        float2 lc = *(const float2*)(last_c + (size_t)n * HDIM + hg);
        float c0 = (float)gg.f[2] * lc.x + (float)gg.f[3] * (float)gg.f[0];
        float c1 = (float)gg.f[6] * lc.y + (float)gg.f[7] * (float)gg.f[4];
        float hd0 = (float)gg.f[1] * ftanh(c0);
        float hd1 = (float)gg.f[5] * ftanh(c1);
        *(float2*)(out_hid  + (size_t)n * HDIM + hg) = make_float2(hd0, hd1);
        *(float2*)(out_cell + (size_t)n * HDIM + hg) = make_float2(c0, c1);
      }
    }
  }
}

extern "C" void kernel_launch(void* const* d_in, const int* in_sizes, int n_in,
                              void* d_out, int out_size, void* d_ws, size_t ws_size,
                              hipStream_t stream) {
  const float* s_in   = (const float*)d_in[0];
  const float* s_out  = (const float*)d_in[1];
  const float* h_in   = (const float*)d_in[2];
  const float* h_out  = (const float*)d_in[3];
  const float* last_c = (const float*)d_in[4];
  const float* w_in   = (const float*)d_in[5];
  const float* w_out  = (const float*)d_in[6];
  const float* u_in   = (const float*)d_in[7];
  const float* u_out  = (const float*)d_in[8];
  const float* b      = (const float*)d_in[9];

  _Float16* wblk = (_Float16*)d_ws;  // needs 819200 B

  pack_w_kernel<<<(NKB * NCOLF * 32 + 255) / 256, 256, 0, stream>>>(
      w_in, w_out, u_in, u_out, wblk);

  float* out_hid  = (float*)d_out;
  float* out_cell = out_hid + (size_t)NROWS * HDIM;

  const int nrb = (NROWS + BM - 1) / BM;  // 1563
  lstm_fused_kernel<<<nrb * 2, NTHREADS, 0, stream>>>(
      s_in, s_out, h_in, h_out, last_c, b, wblk, out_hid, out_cell);
}